// Round 1
// baseline (107.005 us; speedup 1.0000x reference)
//
#include <hip/hip_runtime.h>

#define NINST 23
#define BATCH 10000
#define NCH 64
#define DIM_IN 16
#define DIM_OUT 99
#define CG_DENSE 1875

// Instruction tables (l1, l2, l3) enumerated exactly as the reference:
// i over L_IN1, j over L_IN2, l3 ascending, kept iff l3<=3 and (l1+l2+l3) even.
#define INST_L1  {0,0,0,0,1,1,1,1,1,1,2,2,2,2,2,2,2,3,3,3,3,3,3}
#define INST_L2  {0,1,2,3,0,1,1,2,2,3,0,1,1,2,2,3,3,0,1,2,2,3,3}
#define INST_L3  {0,1,2,3,1,0,2,1,3,2,2,1,3,0,2,1,3,3,2,1,3,0,2}
#define INST_O1  {0,0,0,0,1,1,1,1,1,1,4,4,4,4,4,4,4,9,9,9,9,9,9}
#define INST_O2  {0,1,4,9,0,1,1,4,4,9,0,1,1,4,4,9,9,0,1,4,4,9,9}
#define INST_O3  {0,1,4,9,16,19,20,25,28,35,40,45,48,55,56,61,64,71,78,83,86,93,94}
#define INST_DOF {0,1,10,35,84,93,102,147,192,297,402,427,472,577,602,727,832,1077,1126,1231,1336,1581,1630}

struct cx { double re, im; };
__device__ inline cx cmul(const cx a, const cx b) {
    return cx{a.re * b.re - a.im * b.im, a.re * b.im + a.im * b.re};
}

__device__ inline double fac(int n) {
    const double F[11] = {1.0, 1.0, 2.0, 6.0, 24.0, 120.0, 720.0,
                          5040.0, 40320.0, 362880.0, 3628800.0};
    return F[n];
}

// Racah formula, fp64 (all factorials <= 10! are exact in double)
__device__ double su2_cg(int j1, int m1, int j2, int m2, int j3, int m3) {
    if (m3 != m1 + m2) return 0.0;
    if (j3 < abs(j1 - j2) || j3 > j1 + j2) return 0.0;
    int vmin = max(max(-j1 + j2 + m3, -j1 + m1), 0);
    int vmax = min(min(j2 + j3 + m1, j3 - j1 + j2), j3 + m3);
    double C = (2.0 * j3 + 1.0) *
        (fac(j3 + j1 - j2) * fac(j3 - j1 + j2) * fac(j1 + j2 - j3) *
         fac(j3 + m3) * fac(j3 - m3)) /
        (fac(j1 + j2 + j3 + 1) * fac(j1 - m1) * fac(j1 + m1) *
         fac(j2 - m2) * fac(j2 + m2));
    double S = 0.0;
    for (int v = vmin; v <= vmax; ++v) {
        double t = (fac(j2 + j3 + m1 - v) * fac(j1 - m1 + v)) /
                   (fac(v) * fac(j3 - j1 + j2 - v) * fac(j3 + m3 - v) *
                    fac(v + j1 - j2 - m3));
        S += ((v + j2 + m2) & 1) ? -t : t;
    }
    return sqrt(C) * S;
}

// real SH -> complex SH basis change, matches e3nn (incl. (-i)^l phase)
__device__ void build_q(int l, cx* q) {
    const int n = 2 * l + 1;
    const double is2 = 0.70710678118654752440;
    for (int e = 0; e < n * n; ++e) q[e] = cx{0.0, 0.0};
    for (int m = -l; m < 0; ++m) {
        q[(l + m) * n + (l - m)] = cx{is2, 0.0};
        q[(l + m) * n + (l + m)] = cx{0.0, -is2};
    }
    q[l * n + l] = cx{1.0, 0.0};
    for (int m = 1; m <= l; ++m) {
        double s = (m & 1) ? -1.0 : 1.0;
        q[(l + m) * n + (l + m)] = cx{s * is2, 0.0};
        q[(l + m) * n + (l - m)] = cx{0.0, s * is2};
    }
    cx ph;
    switch (l & 3) {
        case 0:  ph = cx{1.0, 0.0};  break;
        case 1:  ph = cx{0.0, -1.0}; break;
        case 2:  ph = cx{-1.0, 0.0}; break;
        default: ph = cx{0.0, 1.0};  break;
    }
    for (int e = 0; e < n * n; ++e) q[e] = cmul(ph, q[e]);
}

// One block per instruction: compute dense real wigner-3j * sqrt(2*l3+1)
// into cg_out[DOF[inst] .. +n1*n2*n3)
__global__ __launch_bounds__(256) void build_cg_kernel(float* __restrict__ cg_out) {
    const int L1[NINST] = INST_L1;
    const int L2[NINST] = INST_L2;
    const int L3[NINST] = INST_L3;
    const int DOF[NINST] = INST_DOF;

    const int inst = blockIdx.x;
    const int l1 = L1[inst], l2 = L2[inst], l3 = L3[inst];
    const int n1 = 2 * l1 + 1, n2 = 2 * l2 + 1, n3 = 2 * l3 + 1;
    const int tot = n1 * n2 * n3;
    const int tid = threadIdx.x;

    __shared__ double Csu[343];
    __shared__ cx Q1[49], Q2[49], Q3[49];
    __shared__ double Outv[343];
    __shared__ double scale_sh;

    // phase 1: complex-basis CG (real-valued), layout [i][k][n] row-major
    for (int e = tid; e < tot; e += blockDim.x) {
        int nn = e % n3;
        int t = e / n3;
        int k = t % n2;
        int i = t / n2;
        Csu[e] = su2_cg(l1, i - l1, l2, k - l2, l3, nn - l3);
    }
    if (tid == 0) {
        build_q(l1, Q1);
        build_q(l2, Q2);
        build_q(l3, Q3);
    }
    __syncthreads();

    // phase 2: out[j,lc,m] = Re( sum_{i,k,n} Q1[i,j] Q2[k,lc] conj(Q3[n,m]) C[i,k,n] )
    for (int e = tid; e < tot; e += blockDim.x) {
        int m = e % n3;
        int t = e / n3;
        int lc = t % n2;
        int j = t / n2;
        double ar = 0.0;
        for (int i = 0; i < n1; ++i) {
            cx q1 = Q1[i * n1 + j];
            if (q1.re == 0.0 && q1.im == 0.0) continue;
            for (int k = 0; k < n2; ++k) {
                cx q12 = cmul(q1, Q2[k * n2 + lc]);
                if (q12.re == 0.0 && q12.im == 0.0) continue;
                for (int nn = 0; nn < n3; ++nn) {
                    double cc = Csu[(i * n2 + k) * n3 + nn];
                    if (cc == 0.0) continue;
                    cx q3 = Q3[nn * n3 + m];
                    // Re(q12 * conj(q3)) * cc
                    ar += (q12.re * q3.re + q12.im * q3.im) * cc;
                }
            }
        }
        Outv[e] = ar;
    }
    __syncthreads();

    // phase 3: normalize to unit Frobenius norm, * sqrt(2*l3+1)
    if (tid == 0) {
        double ss = 0.0;
        for (int e = 0; e < tot; ++e) ss += Outv[e] * Outv[e];
        scale_sh = sqrt((double)n3) / sqrt(ss);
    }
    __syncthreads();
    for (int e = tid; e < tot; e += blockDim.x)
        cg_out[DOF[inst] + e] = (float)(Outv[e] * scale_sh);
}

// One thread per (batch, channel). channel = lane -> coalesced 256B transactions.
__global__ __launch_bounds__(256) void tp_main(const float* __restrict__ x,
                                              const float* __restrict__ y,
                                              const float* __restrict__ cg,
                                              float* __restrict__ out) {
    const int L1[NINST] = INST_L1;
    const int L2[NINST] = INST_L2;
    const int L3[NINST] = INST_L3;
    const int O1[NINST] = INST_O1;
    const int O2[NINST] = INST_O2;
    const int O3[NINST] = INST_O3;
    const int DOF[NINST] = INST_DOF;

    const int g = blockIdx.x * blockDim.x + threadIdx.x;  // exact grid, no guard
    const int b = g >> 6;
    const int c = g & 63;

    const float* xb = x + b * (DIM_IN * NCH) + c;
    const float* yb = y + b * (DIM_IN * NCH) + c;
    float* ob = out + b * (DIM_OUT * NCH) + c;

    float xv[DIM_IN], yv[DIM_IN];
#pragma unroll
    for (int i = 0; i < DIM_IN; ++i) {
        xv[i] = xb[i * NCH];
        yv[i] = yb[i * NCH];
    }

#pragma unroll
    for (int inst = 0; inst < NINST; ++inst) {
        const int n1 = 2 * L1[inst] + 1;
        const int n2 = 2 * L2[inst] + 1;
        const int n3 = 2 * L3[inst] + 1;
        const int o1 = O1[inst], o2 = O2[inst], o3 = O3[inst], dof = DOF[inst];

        float acc[7];
#pragma unroll
        for (int m = 0; m < 7; ++m) acc[m] = 0.0f;

#pragma unroll
        for (int m1 = 0; m1 < n1; ++m1) {
#pragma unroll
            for (int m2 = 0; m2 < n2; ++m2) {
                const float p = xv[o1 + m1] * yv[o2 + m2];
#pragma unroll
                for (int m3 = 0; m3 < n3; ++m3) {
                    acc[m3] = fmaf(cg[dof + (m1 * n2 + m2) * n3 + m3], p, acc[m3]);
                }
            }
        }
#pragma unroll
        for (int m3 = 0; m3 < n3; ++m3) {
            ob[(o3 + m3) * NCH] = acc[m3];
        }
    }
}

extern "C" void kernel_launch(void* const* d_in, const int* in_sizes, int n_in,
                              void* d_out, int out_size, void* d_ws, size_t ws_size,
                              hipStream_t stream) {
    const float* x = (const float*)d_in[0];
    const float* y = (const float*)d_in[1];
    float* cg = (float*)d_ws;          // 1875 floats of scratch
    float* out = (float*)d_out;

    hipLaunchKernelGGL(build_cg_kernel, dim3(NINST), dim3(256), 0, stream, cg);
    hipLaunchKernelGGL(tp_main, dim3((BATCH * NCH) / 256), dim3(256), 0, stream,
                       x, y, cg, out);
}

// Round 2
// 106.220 us; speedup vs baseline: 1.0074x; 1.0074x over previous
//
#include <hip/hip_runtime.h>

#define NINST 23
#define BATCH 10000
#define NCH 64
#define DIM_IN 16
#define DIM_OUT 99
#define CG_DENSE 1875

// Instruction tables (l1, l2, l3) enumerated exactly as the reference:
// i over L_IN1, j over L_IN2, l3 ascending, kept iff l3<=3 and (l1+l2+l3) even.
#define INST_L1  {0,0,0,0,1,1,1,1,1,1,2,2,2,2,2,2,2,3,3,3,3,3,3}
#define INST_L2  {0,1,2,3,0,1,1,2,2,3,0,1,1,2,2,3,3,0,1,2,2,3,3}
#define INST_L3  {0,1,2,3,1,0,2,1,3,2,2,1,3,0,2,1,3,3,2,1,3,0,2}
#define INST_O1  {0,0,0,0,1,1,1,1,1,1,4,4,4,4,4,4,4,9,9,9,9,9,9}
#define INST_O2  {0,1,4,9,0,1,1,4,4,9,0,1,1,4,4,9,9,0,1,4,4,9,9}
#define INST_O3  {0,1,4,9,16,19,20,25,28,35,40,45,48,55,56,61,64,71,78,83,86,93,94}
#define INST_DOF {0,1,10,35,84,93,102,147,192,297,402,427,472,577,602,727,832,1077,1126,1231,1336,1581,1630}
// 16 (l1,l2) pairs in enumeration order: first instruction index + count of l3's
#define PAIR_FIRST {0,1,2,3,4,5,7,9,10,11,13,15,17,18,19,21}
#define PAIR_NL3   {1,1,1,1,1,2,2,1,1,2,2,2,1,1,2,2}

typedef float f32x4 __attribute__((ext_vector_type(4)));

struct cx { double re, im; };
__device__ inline cx cmul(const cx a, const cx b) {
    return cx{a.re * b.re - a.im * b.im, a.re * b.im + a.im * b.re};
}

__device__ inline double fac(int n) {
    const double F[11] = {1.0, 1.0, 2.0, 6.0, 24.0, 120.0, 720.0,
                          5040.0, 40320.0, 362880.0, 3628800.0};
    return F[n];
}

// Racah formula, fp64 (all factorials <= 10! are exact in double)
__device__ double su2_cg(int j1, int m1, int j2, int m2, int j3, int m3) {
    if (m3 != m1 + m2) return 0.0;
    if (j3 < abs(j1 - j2) || j3 > j1 + j2) return 0.0;
    int vmin = max(max(-j1 + j2 + m3, -j1 + m1), 0);
    int vmax = min(min(j2 + j3 + m1, j3 - j1 + j2), j3 + m3);
    double C = (2.0 * j3 + 1.0) *
        (fac(j3 + j1 - j2) * fac(j3 - j1 + j2) * fac(j1 + j2 - j3) *
         fac(j3 + m3) * fac(j3 - m3)) /
        (fac(j1 + j2 + j3 + 1) * fac(j1 - m1) * fac(j1 + m1) *
         fac(j2 - m2) * fac(j2 + m2));
    double S = 0.0;
    for (int v = vmin; v <= vmax; ++v) {
        double t = (fac(j2 + j3 + m1 - v) * fac(j1 - m1 + v)) /
                   (fac(v) * fac(j3 - j1 + j2 - v) * fac(j3 + m3 - v) *
                    fac(v + j1 - j2 - m3));
        S += ((v + j2 + m2) & 1) ? -t : t;
    }
    return sqrt(C) * S;
}

// real SH -> complex SH basis change, matches e3nn (incl. (-i)^l phase)
__device__ void build_q(int l, cx* q) {
    const int n = 2 * l + 1;
    const double is2 = 0.70710678118654752440;
    for (int e = 0; e < n * n; ++e) q[e] = cx{0.0, 0.0};
    for (int m = -l; m < 0; ++m) {
        q[(l + m) * n + (l - m)] = cx{is2, 0.0};
        q[(l + m) * n + (l + m)] = cx{0.0, -is2};
    }
    q[l * n + l] = cx{1.0, 0.0};
    for (int m = 1; m <= l; ++m) {
        double s = (m & 1) ? -1.0 : 1.0;
        q[(l + m) * n + (l + m)] = cx{s * is2, 0.0};
        q[(l + m) * n + (l - m)] = cx{0.0, s * is2};
    }
    cx ph;
    switch (l & 3) {
        case 0:  ph = cx{1.0, 0.0};  break;
        case 1:  ph = cx{0.0, -1.0}; break;
        case 2:  ph = cx{-1.0, 0.0}; break;
        default: ph = cx{0.0, 1.0};  break;
    }
    for (int e = 0; e < n * n; ++e) q[e] = cmul(ph, q[e]);
}

// One block per instruction: dense real wigner-3j * sqrt(2*l3+1) into cg_out
__global__ __launch_bounds__(256) void build_cg_kernel(float* __restrict__ cg_out) {
    const int L1[NINST] = INST_L1;
    const int L2[NINST] = INST_L2;
    const int L3[NINST] = INST_L3;
    const int DOF[NINST] = INST_DOF;

    const int inst = blockIdx.x;
    const int l1 = L1[inst], l2 = L2[inst], l3 = L3[inst];
    const int n1 = 2 * l1 + 1, n2 = 2 * l2 + 1, n3 = 2 * l3 + 1;
    const int tot = n1 * n2 * n3;
    const int tid = threadIdx.x;

    __shared__ double Csu[343];
    __shared__ cx Q1[49], Q2[49], Q3[49];
    __shared__ double Outv[343];
    __shared__ double Partial[256];
    __shared__ double scale_sh;

    for (int e = tid; e < tot; e += blockDim.x) {
        int nn = e % n3;
        int t = e / n3;
        int k = t % n2;
        int i = t / n2;
        Csu[e] = su2_cg(l1, i - l1, l2, k - l2, l3, nn - l3);
    }
    if (tid == 0) {
        build_q(l1, Q1);
        build_q(l2, Q2);
        build_q(l3, Q3);
    }
    __syncthreads();

    // out[j,lc,m] = Re( sum_{i,k,n} Q1[i,j] Q2[k,lc] conj(Q3[n,m]) C[i,k,n] )
    for (int e = tid; e < tot; e += blockDim.x) {
        int m = e % n3;
        int t = e / n3;
        int lc = t % n2;
        int j = t / n2;
        double ar = 0.0;
        for (int i = 0; i < n1; ++i) {
            cx q1 = Q1[i * n1 + j];
            if (q1.re == 0.0 && q1.im == 0.0) continue;
            for (int k = 0; k < n2; ++k) {
                cx q12 = cmul(q1, Q2[k * n2 + lc]);
                if (q12.re == 0.0 && q12.im == 0.0) continue;
                for (int nn = 0; nn < n3; ++nn) {
                    double cc = Csu[(i * n2 + k) * n3 + nn];
                    if (cc == 0.0) continue;
                    cx q3 = Q3[nn * n3 + m];
                    ar += (q12.re * q3.re + q12.im * q3.im) * cc;
                }
            }
        }
        Outv[e] = ar;
    }
    __syncthreads();

    // parallel Frobenius-norm reduction
    double ps = 0.0;
    for (int e = tid; e < tot; e += blockDim.x) ps += Outv[e] * Outv[e];
    Partial[tid] = ps;
    __syncthreads();
    for (int s = 128; s > 0; s >>= 1) {
        if (tid < s) Partial[tid] += Partial[tid + s];
        __syncthreads();
    }
    if (tid == 0) scale_sh = sqrt((double)n3) / sqrt(Partial[0]);
    __syncthreads();
    for (int e = tid; e < tot; e += blockDim.x)
        cg_out[DOF[inst] + e] = (float)(Outv[e] * scale_sh);
}

// One thread per (batch, 4-channel group). 16 lanes per batch row.
// All loads/stores are dwordx4, nontemporal (pure streaming).
__global__ __launch_bounds__(256, 2) void tp_main(const float* __restrict__ x,
                                                  const float* __restrict__ y,
                                                  const float* __restrict__ cg,
                                                  float* __restrict__ out) {
    const int L1[NINST] = INST_L1;
    const int L2[NINST] = INST_L2;
    const int L3[NINST] = INST_L3;
    const int O1[NINST] = INST_O1;
    const int O2[NINST] = INST_O2;
    const int O3[NINST] = INST_O3;
    const int DOF[NINST] = INST_DOF;
    const int PF[16] = PAIR_FIRST;
    const int PN[16] = PAIR_NL3;

    const int g = blockIdx.x * blockDim.x + threadIdx.x;  // exact grid
    const int b = g >> 4;          // batch row
    const int cl = g & 15;         // channel quad

    const f32x4* x4 = reinterpret_cast<const f32x4*>(x + (size_t)b * (DIM_IN * NCH)) + cl;
    const f32x4* y4 = reinterpret_cast<const f32x4*>(y + (size_t)b * (DIM_IN * NCH)) + cl;
    f32x4* o4 = reinterpret_cast<f32x4*>(out + (size_t)b * (DIM_OUT * NCH)) + cl;

    f32x4 xv[DIM_IN], yv[DIM_IN];
#pragma unroll
    for (int i = 0; i < DIM_IN; ++i) {
        xv[i] = __builtin_nontemporal_load(&x4[i * 16]);
        yv[i] = __builtin_nontemporal_load(&y4[i * 16]);
    }

#pragma unroll
    for (int pr = 0; pr < 16; ++pr) {
        const int i0 = PF[pr];
        const int nl = PN[pr];
        const int n1 = 2 * L1[i0] + 1;
        const int n2 = 2 * L2[i0] + 1;
        const int o1 = O1[i0], o2 = O2[i0];

        f32x4 acc0[7], acc1[7];
#pragma unroll
        for (int m = 0; m < 7; ++m) { acc0[m] = (f32x4)0.0f; acc1[m] = (f32x4)0.0f; }

#pragma unroll
        for (int m1 = 0; m1 < n1; ++m1) {
#pragma unroll
            for (int m2 = 0; m2 < n2; ++m2) {
                const f32x4 p = xv[o1 + m1] * yv[o2 + m2];
                {
                    const int inst = i0;
                    const int n3 = 2 * L3[inst] + 1;
                    const int base = DOF[inst] + (m1 * n2 + m2) * n3;
#pragma unroll
                    for (int m3 = 0; m3 < n3; ++m3)
                        acc0[m3] += cg[base + m3] * p;
                }
                if (nl > 1) {
                    const int inst = i0 + 1;
                    const int n3 = 2 * L3[inst] + 1;
                    const int base = DOF[inst] + (m1 * n2 + m2) * n3;
#pragma unroll
                    for (int m3 = 0; m3 < n3; ++m3)
                        acc1[m3] += cg[base + m3] * p;
                }
            }
        }
        {
            const int inst = i0;
            const int n3 = 2 * L3[inst] + 1;
            const int o3 = O3[inst];
#pragma unroll
            for (int m3 = 0; m3 < n3; ++m3)
                __builtin_nontemporal_store(acc0[m3], &o4[(o3 + m3) * 16]);
        }
        if (nl > 1) {
            const int inst = i0 + 1;
            const int n3 = 2 * L3[inst] + 1;
            const int o3 = O3[inst];
#pragma unroll
            for (int m3 = 0; m3 < n3; ++m3)
                __builtin_nontemporal_store(acc1[m3], &o4[(o3 + m3) * 16]);
        }
    }
}

extern "C" void kernel_launch(void* const* d_in, const int* in_sizes, int n_in,
                              void* d_out, int out_size, void* d_ws, size_t ws_size,
                              hipStream_t stream) {
    const float* x = (const float*)d_in[0];
    const float* y = (const float*)d_in[1];
    float* cg = (float*)d_ws;          // 1875 floats of scratch
    float* out = (float*)d_out;

    hipLaunchKernelGGL(build_cg_kernel, dim3(NINST), dim3(256), 0, stream, cg);
    hipLaunchKernelGGL(tp_main, dim3((BATCH * 16) / 256), dim3(256), 0, stream,
                       x, y, cg, out);
}

// Round 3
// 74.424 us; speedup vs baseline: 1.4378x; 1.4272x over previous
//
#include <hip/hip_runtime.h>

#define BATCH 10000
#define NCH 64
#define DIM_IN 16
#define DIM_OUT 99

typedef float f32x4 __attribute__((ext_vector_type(4)));

// ---------------- compile-time CG construction (C++17 constexpr) ----------------
namespace cgc {

struct cx { double re; double im; };

constexpr cx cmul(cx a, cx b) {
    return cx{a.re * b.re - a.im * b.im, a.re * b.im + a.im * b.re};
}

constexpr double cfact(int n) {
    double r = 1.0;
    for (int i = 2; i <= n; ++i) r *= (double)i;
    return r;
}

constexpr double csqrt(double x) {
    if (x <= 0.0) return 0.0;
    double y = x > 1.0 ? x : 1.0;
    for (int i = 0; i < 100; ++i) y = 0.5 * (y + x / y);
    return y;
}

constexpr int imax(int a, int b) { return a > b ? a : b; }
constexpr int imin(int a, int b) { return a < b ? a : b; }
constexpr int iabs(int a) { return a < 0 ? -a : a; }

// Racah formula (exact ratios of factorials <= 10! in double)
constexpr double su2_cg(int j1, int m1, int j2, int m2, int j3, int m3) {
    if (m3 != m1 + m2) return 0.0;
    if (j3 < iabs(j1 - j2) || j3 > j1 + j2) return 0.0;
    int vmin = imax(imax(-j1 + j2 + m3, -j1 + m1), 0);
    int vmax = imin(imin(j2 + j3 + m1, j3 - j1 + j2), j3 + m3);
    double C = (2.0 * j3 + 1.0) *
        (cfact(j3 + j1 - j2) * cfact(j3 - j1 + j2) * cfact(j1 + j2 - j3) *
         cfact(j3 + m3) * cfact(j3 - m3)) /
        (cfact(j1 + j2 + j3 + 1) * cfact(j1 - m1) * cfact(j1 + m1) *
         cfact(j2 - m2) * cfact(j2 + m2));
    double S = 0.0;
    for (int v = vmin; v <= vmax; ++v) {
        double t = (cfact(j2 + j3 + m1 - v) * cfact(j1 - m1 + v)) /
                   (cfact(v) * cfact(j3 - j1 + j2 - v) * cfact(j3 + m3 - v) *
                    cfact(v + j1 - j2 - m3));
        S += ((v + j2 + m2) & 1) ? -t : t;
    }
    return csqrt(C) * S;
}

// real SH -> complex SH basis change (matches e3nn, incl. (-i)^l phase)
constexpr void fill_q(int l, cx* q) {
    const int n = 2 * l + 1;
    const double is2 = 0.70710678118654752440;
    for (int e = 0; e < n * n; ++e) q[e] = cx{0.0, 0.0};
    for (int m = -l; m < 0; ++m) {
        q[(l + m) * n + (l - m)] = cx{is2, 0.0};
        q[(l + m) * n + (l + m)] = cx{0.0, -is2};
    }
    q[l * n + l] = cx{1.0, 0.0};
    for (int m = 1; m <= l; ++m) {
        double s = (m & 1) ? -1.0 : 1.0;
        q[(l + m) * n + (l + m)] = cx{s * is2, 0.0};
        q[(l + m) * n + (l - m)] = cx{0.0, s * is2};
    }
    cx ph = (l & 3) == 0 ? cx{1.0, 0.0}
          : (l & 3) == 1 ? cx{0.0, -1.0}
          : (l & 3) == 2 ? cx{-1.0, 0.0}
                         : cx{0.0, 1.0};
    for (int e = 0; e < n * n; ++e) q[e] = cmul(ph, q[e]);
}

template<int l1, int l2, int l3>
struct InstCG { float v[(2 * l1 + 1) * (2 * l2 + 1) * (2 * l3 + 1)]; };

// real-basis wigner_3j * sqrt(2*l3+1), unit Frobenius norm before scaling
template<int l1, int l2, int l3>
constexpr InstCG<l1, l2, l3> make_inst() {
    constexpr int n1 = 2 * l1 + 1, n2 = 2 * l2 + 1, n3 = 2 * l3 + 1;
    double C[n1 * n2 * n3] = {};
    for (int i = 0; i < n1; ++i)
        for (int k = 0; k < n2; ++k)
            for (int nn = 0; nn < n3; ++nn)
                C[(i * n2 + k) * n3 + nn] = su2_cg(l1, i - l1, l2, k - l2, l3, nn - l3);
    cx Q1[n1 * n1] = {}; cx Q2[n2 * n2] = {}; cx Q3[n3 * n3] = {};
    fill_q(l1, Q1); fill_q(l2, Q2); fill_q(l3, Q3);
    double R[n1 * n2 * n3] = {};
    double ss = 0.0;
    // out[j,lc,m] = Re( sum_{i,k,n} Q1[i,j] Q2[k,lc] conj(Q3[n,m]) C[i,k,n] )
    for (int j = 0; j < n1; ++j)
        for (int lc = 0; lc < n2; ++lc)
            for (int m = 0; m < n3; ++m) {
                double ar = 0.0;
                for (int i = 0; i < n1; ++i) {
                    cx q1 = Q1[i * n1 + j];
                    if (q1.re == 0.0 && q1.im == 0.0) continue;
                    for (int k = 0; k < n2; ++k) {
                        cx q12 = cmul(q1, Q2[k * n2 + lc]);
                        if (q12.re == 0.0 && q12.im == 0.0) continue;
                        for (int nn = 0; nn < n3; ++nn) {
                            double cc = C[(i * n2 + k) * n3 + nn];
                            if (cc == 0.0) continue;
                            cx q3 = Q3[nn * n3 + m];
                            ar += (q12.re * q3.re + q12.im * q3.im) * cc;  // Re(q12*conj(q3))*cc
                        }
                    }
                }
                R[(j * n2 + lc) * n3 + m] = ar;
                ss += ar * ar;
            }
    double scale = csqrt((double)n3) / csqrt(ss);
    InstCG<l1, l2, l3> T{};
    for (int e = 0; e < n1 * n2 * n3; ++e) T.v[e] = (float)(R[e] * scale);
    return T;
}

}  // namespace cgc

// One instruction: accumulate and store its n3 output slots (each slot written once).
// CG values are compile-time constants -> zero coefficients pruned at compile time.
template<int l1, int l2, int l3, int o1, int o2, int o3>
__device__ __forceinline__ void do_inst(const f32x4* xv, const f32x4* yv, f32x4* o4) {
    constexpr int n1 = 2 * l1 + 1, n2 = 2 * l2 + 1, n3 = 2 * l3 + 1;
    constexpr cgc::InstCG<l1, l2, l3> T = cgc::make_inst<l1, l2, l3>();
    f32x4 acc[n3];
#pragma unroll
    for (int m3 = 0; m3 < n3; ++m3) acc[m3] = (f32x4)0.0f;
#pragma unroll
    for (int m1 = 0; m1 < n1; ++m1) {
#pragma unroll
        for (int m2 = 0; m2 < n2; ++m2) {
            const f32x4 p = xv[o1 + m1] * yv[o2 + m2];  // DCE'd if all c==0
#pragma unroll
            for (int m3 = 0; m3 < n3; ++m3) {
                const float c = T.v[(m1 * n2 + m2) * n3 + m3];  // compile-time literal
                if (c != 0.0f) acc[m3] += c * p;                // folds away when zero
            }
        }
    }
#pragma unroll
    for (int m3 = 0; m3 < n3; ++m3)
        __builtin_nontemporal_store(acc[m3], &o4[(o3 + m3) * 16]);
}

// One thread per (batch, 4-channel group). 16 lanes per batch row; all
// loads/stores dwordx4, fully coalesced 256B/wave-row.
__global__ __launch_bounds__(256) void tp_main(const float* __restrict__ x,
                                               const float* __restrict__ y,
                                               float* __restrict__ out) {
    const int g = blockIdx.x * blockDim.x + threadIdx.x;  // exact grid
    const int b = g >> 4;   // batch row
    const int cl = g & 15;  // channel quad

    const f32x4* x4 = reinterpret_cast<const f32x4*>(x + (size_t)b * (DIM_IN * NCH)) + cl;
    const f32x4* y4 = reinterpret_cast<const f32x4*>(y + (size_t)b * (DIM_IN * NCH)) + cl;
    f32x4* o4 = reinterpret_cast<f32x4*>(out + (size_t)b * (DIM_OUT * NCH)) + cl;

    f32x4 xv[DIM_IN], yv[DIM_IN];
#pragma unroll
    for (int i = 0; i < DIM_IN; ++i) {
        xv[i] = __builtin_nontemporal_load(&x4[i * 16]);
        yv[i] = __builtin_nontemporal_load(&y4[i * 16]);
    }

    // 23 instructions, enumeration order of the reference; o3 offsets precomputed
    do_inst<0,0,0, 0,0,0 >(xv, yv, o4);
    do_inst<0,1,1, 0,1,1 >(xv, yv, o4);
    do_inst<0,2,2, 0,4,4 >(xv, yv, o4);
    do_inst<0,3,3, 0,9,9 >(xv, yv, o4);
    do_inst<1,0,1, 1,0,16>(xv, yv, o4);
    do_inst<1,1,0, 1,1,19>(xv, yv, o4);
    do_inst<1,1,2, 1,1,20>(xv, yv, o4);
    do_inst<1,2,1, 1,4,25>(xv, yv, o4);
    do_inst<1,2,3, 1,4,28>(xv, yv, o4);
    do_inst<1,3,2, 1,9,35>(xv, yv, o4);
    do_inst<2,0,2, 4,0,40>(xv, yv, o4);
    do_inst<2,1,1, 4,1,45>(xv, yv, o4);
    do_inst<2,1,3, 4,1,48>(xv, yv, o4);
    do_inst<2,2,0, 4,4,55>(xv, yv, o4);
    do_inst<2,2,2, 4,4,56>(xv, yv, o4);
    do_inst<2,3,1, 4,9,61>(xv, yv, o4);
    do_inst<2,3,3, 4,9,64>(xv, yv, o4);
    do_inst<3,0,3, 9,0,71>(xv, yv, o4);
    do_inst<3,1,2, 9,1,78>(xv, yv, o4);
    do_inst<3,2,1, 9,4,83>(xv, yv, o4);
    do_inst<3,2,3, 9,4,86>(xv, yv, o4);
    do_inst<3,3,0, 9,9,93>(xv, yv, o4);
    do_inst<3,3,2, 9,9,94>(xv, yv, o4);
}

extern "C" void kernel_launch(void* const* d_in, const int* in_sizes, int n_in,
                              void* d_out, int out_size, void* d_ws, size_t ws_size,
                              hipStream_t stream) {
    const float* x = (const float*)d_in[0];
    const float* y = (const float*)d_in[1];
    float* out = (float*)d_out;
    hipLaunchKernelGGL(tp_main, dim3((BATCH * 16) / 256), dim3(256), 0, stream,
                       x, y, out);
}